// Round 15
// baseline (250.861 us; speedup 1.0000x reference)
//
#include <hip/hip_runtime.h>
#include <hip/hip_bf16.h>
#include <cstdint>
#include <cstddef>

// MHA: B=4, S=2048, D=512, H=8, DH=64. fp32 in/out.
// R24: barrier-free flash via wave-private K/V staging. R23 refuted the
//      occupancy theory (VGPR 72 / LDS 33KB -> same 63us, same 20% occ).
//      Remaining explanation of the stable MfmaUtil33/VALU36 pair: the
//      per-iter s_barrier phase-locks all waves (QK/exp/PV in lockstep ->
//      the two pipes alternate, never overlap; 33+36~70 disjoint). Fix:
//      each wave owns keys [32w..+32) (mod 128) and stages ITS OWN 4KB K +
//      4KB V slice into ITS OWN LDS region (16KB/wave dbuf, 64KB total) ->
//      main loop has ZERO barriers; per-wave vmcnt(0) covers only its own
//      8 GLD16s (issued one compute phase earlier); dbuf hazard wave-local.
//      Waves free-run -> pipes overlap. Epilogue = R22 mq-distributed (one
//      barrier). V rows 64B -> 8-way conflict on 4 vf reads (+~90cy, ok).
//      Cross-wave sum groups differ -> not bit-identical (~2^-20 pert,
//      << bf16 floor; R23 precedent). proj/split kernels R22-exact.

typedef __bf16 bf16;
typedef __attribute__((ext_vector_type(8))) __bf16 bf16x8;
typedef __attribute__((ext_vector_type(4))) __bf16 bf16x4;
typedef __attribute__((ext_vector_type(4))) float floatx4;

#define MFMA16(a, b, c) __builtin_amdgcn_mfma_f32_16x16x32_bf16(a, b, c, 0, 0, 0)

#define GLD16(gp, lp)                                              \
  __builtin_amdgcn_global_load_lds(                                \
      (const __attribute__((address_space(1))) unsigned int*)(gp), \
      (__attribute__((address_space(3))) unsigned int*)(lp), 16, 0, 0)

#define PIPE_TOP()                                     \
  do {                                                 \
    asm volatile("s_waitcnt vmcnt(0)" ::: "memory");   \
    __builtin_amdgcn_s_barrier();                      \
    __builtin_amdgcn_sched_barrier(0);                 \
  } while (0)

#define WAVE_VM_WAIT()                                 \
  do {                                                 \
    asm volatile("s_waitcnt vmcnt(0)" ::: "memory");   \
    __builtin_amdgcn_sched_barrier(0);                 \
  } while (0)

#define LGKM_BARRIER()                                 \
  do {                                                 \
    asm volatile("s_waitcnt lgkmcnt(0)" ::: "memory"); \
    __builtin_amdgcn_sched_barrier(0);                 \
    __builtin_amdgcn_s_barrier();                      \
    __builtin_amdgcn_sched_barrier(0);                 \
  } while (0)

__device__ __forceinline__ void split2(float x, bf16& hi, bf16& lo) {
  hi = (bf16)x;
  lo = (bf16)(x - (float)hi);
}

// ---------------------------------------------------------------------------
// Split + transpose the 4 weight matrices: wt[w][n][k] = W_w[k][n] as hi/lo bf16
// ---------------------------------------------------------------------------
__global__ __launch_bounds__(256) void k_split_w(
    const float* __restrict__ Wq, const float* __restrict__ Wk,
    const float* __restrict__ Wv, const float* __restrict__ Wo,
    bf16* __restrict__ wt_hi, bf16* __restrict__ wt_lo) {
  __shared__ float tile[64][65];
  const int w = blockIdx.z;
  const float* W = (w == 0) ? Wq : (w == 1) ? Wk : (w == 2) ? Wv : Wo;
  const int kb = blockIdx.y * 64, nb = blockIdx.x * 64;
  const int tid = threadIdx.x;
  const int col = tid & 63, rbase = tid >> 6;
#pragma unroll
  for (int i = 0; i < 16; i++) {
    int row = rbase + i * 4;
    tile[row][col] = W[(size_t)(kb + row) * 512 + nb + col];
  }
  __syncthreads();
#pragma unroll
  for (int i = 0; i < 16; i++) {
    int nrow = rbase + i * 4;
    float v = tile[col][nrow];
    bf16 hi, lo;
    split2(v, hi, lo);
    size_t o = (size_t)w * 262144 + (size_t)(nb + nrow) * 512 + (kb + col);
    wt_hi[o] = hi;
    wt_lo[o] = lo;
  }
}

// ---------------------------------------------------------------------------
// Pre-split X (q,k,v inputs) into bf16 hi/lo. Elementwise, memory-bound.
// ---------------------------------------------------------------------------
__global__ __launch_bounds__(256) void k_split_x(
    const float* __restrict__ Xq, const float* __restrict__ Xk,
    const float* __restrict__ Xv,
    bf16* __restrict__ Xh, bf16* __restrict__ Xl) {
  const int total = 3 * 1048576;  // float4 granules (3 x 4M floats)
  for (int j = blockIdx.x * blockDim.x + threadIdx.x; j < total;
       j += gridDim.x * blockDim.x) {
    int w = j >> 20, off = j & 1048575;
    const float* X = (w == 0) ? Xq : (w == 1) ? Xk : Xv;
    floatx4 v = *(const floatx4*)(X + (size_t)off * 4);
    bf16x4 hv, lv;
#pragma unroll
    for (int r = 0; r < 4; r++) {
      bf16 h, l;
      split2(v[r], h, l);
      hv[r] = h; lv[r] = l;
    }
    *(bf16x4*)(Xh + (size_t)w * 4194304 + (size_t)off * 4) = hv;
    *(bf16x4*)(Xl + (size_t)w * 4194304 + (size_t)off * 4) = lv;
  }
}

// ---------------------------------------------------------------------------
// QKV projection, 128x128 C-tile, BK=32, pure-bf16 operands (pre-split X).
// Single-buffer GLD16 staging (32KB) + two-phase sync + setprio on MFMA
// cluster. (256,3) -> 3 blk/CU. grid 768, block 256. (R22-exact)
// ---------------------------------------------------------------------------
__global__ __launch_bounds__(256, 3) void k_proj_qkv(
    const bf16* __restrict__ Xh, const bf16* __restrict__ Xl,
    const bf16* __restrict__ wt_hi, const bf16* __restrict__ wt_lo,
    bf16* __restrict__ Q_hi, bf16* __restrict__ Q_lo,
    bf16* __restrict__ K, bf16* __restrict__ Vt) {
  const int P = blockIdx.x;
  const int c_all = P >> 5, within = P & 31;
  const int n_idx = within >> 3, i8 = within & 7;
  const int which = c_all >> 3;
  const int g = ((c_all & 7) << 3) | i8;  // m-group 0..63
  const int m0 = g * 128, n0 = n_idx * 128;

  const uint8_t* Ahb = (const uint8_t*)(Xh + (size_t)which * 4194304);
  const uint8_t* Alb = (const uint8_t*)(Xl + (size_t)which * 4194304);
  const uint8_t* Bhb = (const uint8_t*)(wt_hi + (size_t)which * 262144);
  const uint8_t* Blb = (const uint8_t*)(wt_lo + (size_t)which * 262144);
  const int tid = threadIdx.x, wave = tid >> 6, lane = tid & 63;
  const int l15 = lane & 15, l4 = lane >> 4;
  const int Am0 = (wave & 1) * 64, Bn0 = (wave >> 1) * 64;

  __shared__ bf16 sAh[128 * 32], sAl[128 * 32];  // 8 KB each
  __shared__ bf16 sBh[128 * 32], sBl[128 * 32];  // 8 KB each

  int aoff[2], boff[2], dstp[2];
#pragma unroll
  for (int p = 0; p < 2; p++) {
    int slot = p * 256 + tid;
    int row = slot >> 2, phys = slot & 3, lg = phys ^ (row & 3);
    aoff[p] = (m0 + row) * 1024 + lg * 16;
    boff[p] = (n0 + row) * 1024 + lg * 16;
    dstp[p] = slot * 16;
  }

  floatx4 acc[4][4];
#pragma unroll
  for (int i = 0; i < 4; i++)
#pragma unroll
    for (int j = 0; j < 4; j++) acc[i][j] = {0.f, 0.f, 0.f, 0.f};

  // prologue: issue stage(0)
#pragma unroll
  for (int p = 0; p < 2; p++) {
    GLD16(Ahb + aoff[p], (char*)sAh + dstp[p]);
    GLD16(Alb + aoff[p], (char*)sAl + dstp[p]);
    GLD16(Bhb + boff[p], (char*)sBh + dstp[p]);
    GLD16(Blb + boff[p], (char*)sBl + dstp[p]);
  }

  for (int kb = 0; kb < 512; kb += 32) {
    PIPE_TOP();  // stage(kb) landed

    bf16x8 ah[4], al[4], bhf[4], blf[4];
#pragma unroll
    for (int mt = 0; mt < 4; mt++) {
      int row = Am0 + mt * 16 + l15, r3 = row & 3;
      ah[mt] = *(const bf16x8*)((const char*)sAh + row * 64 + ((l4 ^ r3) * 16));
      al[mt] = *(const bf16x8*)((const char*)sAl + row * 64 + ((l4 ^ r3) * 16));
    }
#pragma unroll
    for (int nt = 0; nt < 4; nt++) {
      int row = Bn0 + nt * 16 + l15, r3 = row & 3;
      bhf[nt] = *(const bf16x8*)((const char*)sBh + row * 64 + ((l4 ^ r3) * 16));
      blf[nt] = *(const bf16x8*)((const char*)sBl + row * 64 + ((l4 ^ r3) * 16));
    }

    LGKM_BARRIER();  // all waves consumed -> safe to overwrite

    if (kb + 32 < 512) {
      const int nkb = kb + 32;
#pragma unroll
      for (int p = 0; p < 2; p++) {
        GLD16(Ahb + aoff[p] + nkb * 2, (char*)sAh + dstp[p]);
        GLD16(Alb + aoff[p] + nkb * 2, (char*)sAl + dstp[p]);
        GLD16(Bhb + boff[p] + nkb * 2, (char*)sBh + dstp[p]);
        GLD16(Blb + boff[p] + nkb * 2, (char*)sBl + dstp[p]);
      }
    }

    __builtin_amdgcn_s_setprio(1);
#pragma unroll
    for (int nt = 0; nt < 4; nt++) {
#pragma unroll
      for (int mt = 0; mt < 4; mt++) {
        acc[mt][nt] = MFMA16(ah[mt], bhf[nt], acc[mt][nt]);
        acc[mt][nt] = MFMA16(ah[mt], blf[nt], acc[mt][nt]);
        acc[mt][nt] = MFMA16(al[mt], bhf[nt], acc[mt][nt]);
      }
    }
    __builtin_amdgcn_s_setprio(0);
  }

  const float scale = (which == 0) ? 0.125f : (which == 1) ? 1.44269504f : 1.0f;
#pragma unroll
  for (int mt = 0; mt < 4; mt++) {
#pragma unroll
    for (int nt = 0; nt < 4; nt++) {
      int m_base = m0 + Am0 + mt * 16 + l4 * 4;  // 4 consecutive rows (s)
      int n = n0 + Bn0 + nt * 16 + l15;          // h*64+d
      int h = (n >> 6) & 7, d = n & 63;
      if (which == 2) {
        // slot-permuted packed V^T store: keys 16t+4q+r -> column 8q+4t+r
        int kbase = m_base & 2047, b = m_base >> 11;
        int a32 = kbase & ~31, v = (kbase >> 2) & 7;
        int sbase = a32 + 8 * (v & 3) + 4 * (v >> 2);
        bf16x4 pv;
#pragma unroll
        for (int r = 0; r < 4; r++) pv[r] = (bf16)acc[mt][nt][r];
        *(bf16x4*)&Vt[((size_t)(b * 8 + h) * 64 + d) * 2048 + sbase] = pv;
      } else {
#pragma unroll
        for (int r = 0; r < 4; r++) {
          int m = m_base + r;
          int b = m >> 11, s = m & 2047;
          float v = acc[mt][nt][r] * scale;
          size_t o = ((size_t)(b * 8 + h) * 2048 + s) * 64 + d;
          if (which == 0) {
            bf16 hi, lo;
            split2(v, hi, lo);
            Q_hi[o] = hi; Q_lo[o] = lo;
          } else {
            K[o] = (bf16)v;  // single bf16 K
          }
        }
      }
    }
  }
}

// ---------------------------------------------------------------------------
// Flash attention, BARRIER-FREE main loop. grid 1024, block 256 = 4 waves.
// Wave w owns keys [32w..32w+32) of each 128-key stride: its tile t covers
// keys t*128 + w*32 .. +32. Wave-private LDS region (16KB: K/V dbuf), its
// own GLD16s, per-wave vmcnt(0). No s_barrier until the epilogue.
// smem: wave regions 4 x 16KB = 64KB (K@cur*8192, V@cur*8192+4096) |
// lbuf @65536. Epilogue: R22 mq-distributed (red aliases wave regions).
// ---------------------------------------------------------------------------
__global__ __launch_bounds__(256, 2) void k_flash(
    const bf16* __restrict__ Q_hi, const bf16* __restrict__ Q_lo,
    const bf16* __restrict__ K, const bf16* __restrict__ Vt,
    bf16* __restrict__ O_hi, bf16* __restrict__ O_lo) {
  const int P = blockIdx.x;
  const int hi4 = P >> 8, rem = P & 255;
  const int qt = rem >> 3;
  const int bh = hi4 * 8 + (rem & 7);
  const int b = bh >> 3, h = bh & 7;
  const int tid = threadIdx.x, wave = tid >> 6, lane = tid & 63;
  const int l15 = lane & 15, l4 = lane >> 4;
  const int q0 = qt * 64;

  __shared__ char smem[65536 + 1024];
  float* lbuf = (float*)(smem + 65536);
  char* wbase = smem + wave * 16384;

  const uint8_t* Kb = (const uint8_t*)K + (size_t)bh * 2048 * 128;
  const uint8_t* Vb = (const uint8_t*)Vt + (size_t)bh * 64 * 4096;

  // wave-local staging offsets: slot = p*64 + lane (0..255)
  // K slice: 32 rows x 128B (4KB); V slice: 64 dh rows x 64B (4KB).
  int koff[4], voff[4], dstk[4];
#pragma unroll
  for (int p = 0; p < 4; p++) {
    int slot = p * 64 + lane;
    int krow = slot >> 3, kphys = slot & 7, klg = kphys ^ (krow & 7);
    koff[p] = krow * 128 + klg * 16;  // + (j0 key base)*128 at issue
    int vrow = slot >> 2, vphys = slot & 3, vlg = vphys ^ (vrow & 3);
    voff[p] = vrow * 4096 + vlg * 16;  // + j0*2 at issue
    dstk[p] = slot * 16;
  }

  // prologue: stage wave's tile 0 (keys wave*32 .. +32) into buf 0
  {
    const size_t j0 = (size_t)wave * 32;
#pragma unroll
    for (int p = 0; p < 4; p++) {
      GLD16(Kb + j0 * 128 + koff[p], wbase + dstk[p]);
      GLD16(Vb + j0 * 2 + voff[p], wbase + 4096 + dstk[p]);
    }
  }

  // Q fragments (B operand): lane holds Q[q=l15][dh=l4*8+j]
  bf16x8 qh[4][2], ql[4][2];
#pragma unroll
  for (int nt = 0; nt < 4; nt++) {
    const bf16* ph = Q_hi + ((size_t)bh * 2048 + q0 + nt * 16 + l15) * 64 + l4 * 8;
    const bf16* pl = Q_lo + ((size_t)bh * 2048 + q0 + nt * 16 + l15) * 64 + l4 * 8;
    qh[nt][0] = *(const bf16x8*)ph;
    qh[nt][1] = *(const bf16x8*)(ph + 32);
    ql[nt][0] = *(const bf16x8*)pl;
    ql[nt][1] = *(const bf16x8*)(pl + 32);
  }

  float lp[4] = {0.f, 0.f, 0.f, 0.f};  // l partial per q-tile (q = nt*16+l15)
  floatx4 oacc[4][4];
#pragma unroll
  for (int i = 0; i < 4; i++)
#pragma unroll
    for (int j = 0; j < 4; j++) oacc[i][j] = {0.f, 0.f, 0.f, 0.f};

  int cur = 0;
  for (int t = 0; t < 16; t++) {
    WAVE_VM_WAIT();  // this wave's stage(t) landed (issued one iter ago)

    const char* kbuf = wbase + cur * 8192;
    const char* vbuf = kbuf + 4096;

    // K fragments (wave-local rows 0..31)
    bf16x8 kf[2][2];  // [ks][kt]
#pragma unroll
    for (int kt = 0; kt < 2; kt++) {
      int row = kt * 16 + l15, r7 = row & 7;
#pragma unroll
      for (int ks = 0; ks < 2; ks++)
        kf[ks][kt] =
            *(const bf16x8*)(kbuf + row * 128 + (((ks * 4 + l4) ^ r7) * 16));
    }
    // V fragments (64B rows; 8-way bank conflict accepted)
    bf16x8 vf[4];
#pragma unroll
    for (int nt = 0; nt < 4; nt++) {
      int row = nt * 16 + l15;
      vf[nt] = *(const bf16x8*)(vbuf + row * 64 + ((l4 ^ (row & 3)) * 16));
    }

    // issue next tile's stage into the other half of this wave's region
    if (t + 1 < 16) {
      char* nb = wbase + (cur ^ 1) * 8192;
      const size_t nj = (size_t)(t + 1) * 128 + (size_t)wave * 32;
#pragma unroll
      for (int p = 0; p < 4; p++) {
        GLD16(Kb + nj * 128 + koff[p], nb + dstk[p]);
        GLD16(Vb + nj * 2 + voff[p], nb + 4096 + dstk[p]);
      }
    }

    // S^T = K Q^T - 24: sc[kt][nt] C-tile: row=key(16), col=q (l15)
    floatx4 sc[2][4];
#pragma unroll
    for (int kt = 0; kt < 2; kt++)
#pragma unroll
      for (int nt = 0; nt < 4; nt++)
        sc[kt][nt] = {-24.f, -24.f, -24.f, -24.f};
#pragma unroll
    for (int ks = 0; ks < 2; ks++) {
#pragma unroll
      for (int nt = 0; nt < 4; nt++) {
        sc[0][nt] = MFMA16(kf[ks][0], qh[nt][ks], sc[0][nt]);
        sc[0][nt] = MFMA16(kf[ks][0], ql[nt][ks], sc[0][nt]);
        sc[1][nt] = MFMA16(kf[ks][1], qh[nt][ks], sc[1][nt]);
        sc[1][nt] = MFMA16(kf[ks][1], ql[nt][ks], sc[1][nt]);
      }
    }

    // p = exp2(s); pf[nt] directly the PV A-operand (slot = quad*8 + 4*kt + r)
    bf16x8 pf[4];
#pragma unroll
    for (int nt = 0; nt < 4; nt++) {
#pragma unroll
      for (int r = 0; r < 4; r++) {
        float p0 = __builtin_amdgcn_exp2f(sc[0][nt][r]);
        float p1 = __builtin_amdgcn_exp2f(sc[1][nt][r]);
        lp[nt] += p0 + p1;
        pf[nt][r] = (bf16)p0;
        pf[nt][4 + r] = (bf16)p1;
      }
    }

    // O += P V over this wave's 32 key slots
#pragma unroll
    for (int nt = 0; nt < 4; nt++) {
#pragma unroll
      for (int mq = 0; mq < 4; mq++)
        oacc[mq][nt] = MFMA16(pf[mq], vf[nt], oacc[mq][nt]);
    }
    cur ^= 1;
  }

  // ---- epilogue: single-phase mq-distributed reduction + write (R22) ----
#pragma unroll
  for (int nt = 0; nt < 4; nt++) {
    lp[nt] += __shfl_xor(lp[nt], 16, 64);
    lp[nt] += __shfl_xor(lp[nt], 32, 64);
  }
  __syncthreads();  // all waves done with their regions before aliasing red

  if (l4 == 0) {
#pragma unroll
    for (int nt = 0; nt < 4; nt++) lbuf[wave * 64 + nt * 16 + l15] = lp[nt];
  }
  // red slice (src, mq, nt): base floatx4 index (src*16 + mq*4 + nt)*64 + lane
  floatx4* red = (floatx4*)smem;
#pragma unroll
  for (int mq = 0; mq < 4; mq++) {
    if (mq != wave) {
#pragma unroll
      for (int nt = 0; nt < 4; nt++)
        red[(wave * 16 + mq * 4 + nt) * 64 + lane] = oacc[mq][nt];
    }
  }
  __syncthreads();

  {
    const int mq = wave;  // this wave finalizes q rows q0 + mq*16 .. +16
    floatx4 fin[4];
#pragma unroll
    for (int nt = 0; nt < 4; nt++) {
      floatx4 s0 = (wave == 0) ? oacc[mq][nt]
                               : red[(0 * 16 + mq * 4 + nt) * 64 + lane];
      floatx4 s1 = (wave == 1) ? oacc[mq][nt]
                               : red[(1 * 16 + mq * 4 + nt) * 64 + lane];
      floatx4 s2 = (wave == 2) ? oacc[mq][nt]
                               : red[(2 * 16 + mq * 4 + nt) * 64 + lane];
      floatx4 s3 = (wave == 3) ? oacc[mq][nt]
                               : red[(3 * 16 + mq * 4 + nt) * 64 + lane];
      fin[nt] = s0 + ((s1 + s2) + s3);
    }
    float ltw = lbuf[mq * 16 + l15] + lbuf[64 + mq * 16 + l15] +
                lbuf[128 + mq * 16 + l15] + lbuf[192 + mq * 16 + l15];
    float rlw[4];
#pragma unroll
    for (int r = 0; r < 4; r++)
      rlw[r] = 1.0f / __shfl(ltw, (lane & 48) | (l4 * 4 + r), 64);
#pragma unroll
    for (int nt = 0; nt < 4; nt++) {
#pragma unroll
      for (int r = 0; r < 4; r++) {
        float v = fin[nt][r] * rlw[r];
        int gs = q0 + mq * 16 + l4 * 4 + r;
        int gd = h * 64 + nt * 16 + l15;
        size_t o = ((size_t)b * 2048 + gs) * 512 + gd;
        bf16 hi, lo;
        split2(v, hi, lo);
        O_hi[o] = hi;
        O_lo[o] = lo;
      }
    }
  }
}

// ---------------------------------------------------------------------------
// Output projection, 64x128 C-tile, BK=32, single-buffer (24KB) two-phase
// sync + setprio. grid 512, m-major -> 2 blocks/CU. (R22-exact)
// ---------------------------------------------------------------------------
__global__ __launch_bounds__(256, 2) void k_proj_out(
    const bf16* __restrict__ O_hi, const bf16* __restrict__ O_lo,
    const bf16* __restrict__ wt_hi, const bf16* __restrict__ wt_lo,
    float* __restrict__ out) {
  const int P = blockIdx.x;
  const int g = P & 127, n_idx = P >> 7;
  const int m0 = g * 64, n0 = n_idx * 128;

  const uint8_t* Ahb = (const uint8_t*)O_hi;
  const uint8_t* Alb = (const uint8_t*)O_lo;
  const uint8_t* Bhb = (const uint8_t*)(wt_hi + (size_t)3 * 262144);
  const uint8_t* Blb = (const uint8_t*)(wt_lo + (size_t)3 * 262144);
  const int tid = threadIdx.x, wave = tid >> 6, lane = tid & 63;
  const int l15 = lane & 15, l4 = lane >> 4;
  const int Am0 = (wave & 1) * 32, Bn0 = (wave >> 1) * 64;

  __shared__ bf16 sAh[64 * 32], sAl[64 * 32];    // 4 KB each
  __shared__ bf16 sBh[128 * 32], sBl[128 * 32];  // 8 KB each

  int aoff, adst;
  {
    int slot = tid;
    int row = slot >> 2, phys = slot & 3, lg = phys ^ (row & 3);
    aoff = (m0 + row) * 1024 + lg * 16;
    adst = slot * 16;
  }
  int boff[2], bdst[2];
#pragma unroll
  for (int p = 0; p < 2; p++) {
    int slot = p * 256 + tid;
    int row = slot >> 2, phys = slot & 3, lg = phys ^ (row & 3);
    boff[p] = (n0 + row) * 1024 + lg * 16;
    bdst[p] = slot * 16;
  }

  floatx4 acc[2][4];
#pragma unroll
  for (int i = 0; i < 2; i++)
#pragma unroll
    for (int j = 0; j < 4; j++) acc[i][j] = {0.f, 0.f, 0.f, 0.f};

  // prologue: issue stage(0)
  GLD16(Ahb + aoff, (char*)sAh + adst);
  GLD16(Alb + aoff, (char*)sAl + adst);
#pragma unroll
  for (int p = 0; p < 2; p++) {
    GLD16(Bhb + boff[p], (char*)sBh + bdst[p]);
    GLD16(Blb + boff[p], (char*)sBl + bdst[p]);
  }

  for (int kb = 0; kb < 512; kb += 32) {
    PIPE_TOP();

    bf16x8 ah[2], al[2], bhf[4], blf[4];
#pragma unroll
    for (int mt = 0; mt < 2; mt++) {
      int row = Am0 + mt * 16 + l15, r3 = row & 3;
      ah[mt] = *(const bf16x8*)((const char*)sAh + row * 64 + ((l4 ^ r3) * 16));
      al[mt] = *(const bf16x8*)((const char*)sAl + row * 64 + ((l4 ^ r3) * 16));
    }
#pragma unroll
    for (int nt = 0; nt < 4; nt++) {
      int row = Bn0 + nt * 16 + l15, r3 = row & 3;
      bhf[nt] = *(const bf16x8*)((const char*)sBh + row * 64 + ((l4 ^ r3) * 16));
      blf[nt] = *(const bf16x8*)((const char*)sBl + row * 64 + ((l4 ^ r3) * 16));
    }

    LGKM_BARRIER();

    if (kb + 32 < 512) {
      const int nkb = kb + 32;
      GLD16(Ahb + aoff + nkb * 2, (char*)sAh + adst);
      GLD16(Alb + aoff + nkb * 2, (char*)sAl + adst);
#pragma unroll
      for (int p = 0; p < 2; p++) {
        GLD16(Bhb + boff[p] + nkb * 2, (char*)sBh + bdst[p]);
        GLD16(Blb + boff[p] + nkb * 2, (char*)sBl + bdst[p]);
      }
    }

    __builtin_amdgcn_s_setprio(1);
#pragma unroll
    for (int nt = 0; nt < 4; nt++) {
#pragma unroll
      for (int mt = 0; mt < 2; mt++) {
        acc[mt][nt] = MFMA16(ah[mt], bhf[nt], acc[mt][nt]);
        acc[mt][nt] = MFMA16(ah[mt], blf[nt], acc[mt][nt]);
        acc[mt][nt] = MFMA16(al[mt], bhf[nt], acc[mt][nt]);
      }
    }
    __builtin_amdgcn_s_setprio(0);
  }
#pragma unroll
  for (int mt = 0; mt < 2; mt++) {
#pragma unroll
    for (int nt = 0; nt < 4; nt++) {
#pragma unroll
      for (int r = 0; r < 4; r++) {
        int m = m0 + Am0 + mt * 16 + l4 * 4 + r;
        int n = n0 + Bn0 + nt * 16 + l15;
        out[(size_t)m * 512 + n] = acc[mt][nt][r];
      }
    }
  }
}

// ---------------------------------------------------------------------------
extern "C" void kernel_launch(void* const* d_in, const int* in_sizes, int n_in,
                              void* d_out, int out_size, void* d_ws, size_t ws_size,
                              hipStream_t stream) {
  (void)in_sizes; (void)n_in; (void)out_size; (void)ws_size;
  const float* Xq = (const float*)d_in[0];
  const float* Xk = (const float*)d_in[1];
  const float* Xv = (const float*)d_in[2];
  const float* Wq = (const float*)d_in[3];
  const float* Wk = (const float*)d_in[4];
  const float* Wv = (const float*)d_in[5];
  const float* Wo = (const float*)d_in[6];
  float* out = (float*)d_out;

  char* ws = (char*)d_ws;
  size_t off = 0;
  auto alloc = [&](size_t n) {
    void* p = ws + off;
    off += (n + 255) & ~(size_t)255;
    return p;
  };
  const size_t NW = 4 * 262144;
  const size_t NE = 4194304;       // 4*2048*512
  const size_t NX = 3 * 4194304;   // all three X inputs
  bf16* wt_hi = (bf16*)alloc(NW * 2);
  bf16* wt_lo = (bf16*)alloc(NW * 2);
  bf16* Qh = (bf16*)alloc(NE * 2);
  bf16* Ql = (bf16*)alloc(NE * 2);
  bf16* Kk = (bf16*)alloc(NE * 2);
  bf16* Vt = (bf16*)alloc(NE * 2);
  // Xh/Xl alias Oh/Ol: Xh,Xl dead before flash writes Oh,Ol.
  char* shared_region = (char*)alloc(2 * NX * 2);
  bf16* Xh = (bf16*)shared_region;
  bf16* Xl = Xh + NX;
  bf16* Oh = (bf16*)shared_region;
  bf16* Ol = Oh + NE;

  k_split_w<<<dim3(8, 8, 4), dim3(256), 0, stream>>>(Wq, Wk, Wv, Wo, wt_hi, wt_lo);
  k_split_x<<<dim3(2048), dim3(256), 0, stream>>>(Xq, Xk, Xv, Xh, Xl);
  k_proj_qkv<<<dim3(768), dim3(256), 0, stream>>>(Xh, Xl, wt_hi, wt_lo,
                                                  Qh, Ql, Kk, Vt);
  k_flash<<<dim3(1024), dim3(256), 0, stream>>>(Qh, Ql, Kk, Vt, Oh, Ol);
  k_proj_out<<<dim3(512), dim3(256), 0, stream>>>(Oh, Ol, wt_hi, wt_lo, out);
}

// Round 16
// 220.701 us; speedup vs baseline: 1.1367x; 1.1367x over previous
//
#include <hip/hip_runtime.h>
#include <hip/hip_bf16.h>
#include <cstdint>
#include <cstddef>

// MHA: B=4, S=2048, D=512, H=8, DH=64. fp32 in/out.
// R25: lock-in of best-measured components (R22-exact) + one safe tweak.
//      R24 post-mortem: wave-private staging spilled (WRITE 177MB) and
//      broke request coalescing (FETCH 48MB) -> 88us; reverted. Structural
//      experiments on flash (R12/R15/R20/R24) all regressed; flash 62.6us
//      (R22) reproduced across 4 builds. Tweak: flash stage-issue for tile
//      j+1 hoisted to directly after PIPE_TOP (independent of tile-j
//      ds_reads: writes buf^1 whose readers passed the barrier) -> loads
//      get ~100cy more lead before next vmcnt(0). Bit-identical.

typedef __bf16 bf16;
typedef __attribute__((ext_vector_type(8))) __bf16 bf16x8;
typedef __attribute__((ext_vector_type(4))) __bf16 bf16x4;
typedef __attribute__((ext_vector_type(4))) float floatx4;

#define MFMA16(a, b, c) __builtin_amdgcn_mfma_f32_16x16x32_bf16(a, b, c, 0, 0, 0)

#define GLD16(gp, lp)                                              \
  __builtin_amdgcn_global_load_lds(                                \
      (const __attribute__((address_space(1))) unsigned int*)(gp), \
      (__attribute__((address_space(3))) unsigned int*)(lp), 16, 0, 0)

#define PIPE_TOP()                                     \
  do {                                                 \
    asm volatile("s_waitcnt vmcnt(0)" ::: "memory");   \
    __builtin_amdgcn_s_barrier();                      \
    __builtin_amdgcn_sched_barrier(0);                 \
  } while (0)

#define LGKM_BARRIER()                                 \
  do {                                                 \
    asm volatile("s_waitcnt lgkmcnt(0)" ::: "memory"); \
    __builtin_amdgcn_sched_barrier(0);                 \
    __builtin_amdgcn_s_barrier();                      \
    __builtin_amdgcn_sched_barrier(0);                 \
  } while (0)

__device__ __forceinline__ void split2(float x, bf16& hi, bf16& lo) {
  hi = (bf16)x;
  lo = (bf16)(x - (float)hi);
}

// ---------------------------------------------------------------------------
// Split + transpose the 4 weight matrices: wt[w][n][k] = W_w[k][n] as hi/lo bf16
// ---------------------------------------------------------------------------
__global__ __launch_bounds__(256) void k_split_w(
    const float* __restrict__ Wq, const float* __restrict__ Wk,
    const float* __restrict__ Wv, const float* __restrict__ Wo,
    bf16* __restrict__ wt_hi, bf16* __restrict__ wt_lo) {
  __shared__ float tile[64][65];
  const int w = blockIdx.z;
  const float* W = (w == 0) ? Wq : (w == 1) ? Wk : (w == 2) ? Wv : Wo;
  const int kb = blockIdx.y * 64, nb = blockIdx.x * 64;
  const int tid = threadIdx.x;
  const int col = tid & 63, rbase = tid >> 6;
#pragma unroll
  for (int i = 0; i < 16; i++) {
    int row = rbase + i * 4;
    tile[row][col] = W[(size_t)(kb + row) * 512 + nb + col];
  }
  __syncthreads();
#pragma unroll
  for (int i = 0; i < 16; i++) {
    int nrow = rbase + i * 4;
    float v = tile[col][nrow];
    bf16 hi, lo;
    split2(v, hi, lo);
    size_t o = (size_t)w * 262144 + (size_t)(nb + nrow) * 512 + (kb + col);
    wt_hi[o] = hi;
    wt_lo[o] = lo;
  }
}

// ---------------------------------------------------------------------------
// Pre-split X (q,k,v inputs) into bf16 hi/lo. Elementwise, memory-bound.
// ---------------------------------------------------------------------------
__global__ __launch_bounds__(256) void k_split_x(
    const float* __restrict__ Xq, const float* __restrict__ Xk,
    const float* __restrict__ Xv,
    bf16* __restrict__ Xh, bf16* __restrict__ Xl) {
  const int total = 3 * 1048576;  // float4 granules (3 x 4M floats)
  for (int j = blockIdx.x * blockDim.x + threadIdx.x; j < total;
       j += gridDim.x * blockDim.x) {
    int w = j >> 20, off = j & 1048575;
    const float* X = (w == 0) ? Xq : (w == 1) ? Xk : Xv;
    floatx4 v = *(const floatx4*)(X + (size_t)off * 4);
    bf16x4 hv, lv;
#pragma unroll
    for (int r = 0; r < 4; r++) {
      bf16 h, l;
      split2(v[r], h, l);
      hv[r] = h; lv[r] = l;
    }
    *(bf16x4*)(Xh + (size_t)w * 4194304 + (size_t)off * 4) = hv;
    *(bf16x4*)(Xl + (size_t)w * 4194304 + (size_t)off * 4) = lv;
  }
}

// ---------------------------------------------------------------------------
// QKV projection, 128x128 C-tile, BK=32, pure-bf16 operands (pre-split X).
// Single-buffer GLD16 staging (32KB) + two-phase sync + setprio on MFMA
// cluster. (256,3) -> 3 blk/CU. grid 768, block 256. (R22-exact)
// ---------------------------------------------------------------------------
__global__ __launch_bounds__(256, 3) void k_proj_qkv(
    const bf16* __restrict__ Xh, const bf16* __restrict__ Xl,
    const bf16* __restrict__ wt_hi, const bf16* __restrict__ wt_lo,
    bf16* __restrict__ Q_hi, bf16* __restrict__ Q_lo,
    bf16* __restrict__ K, bf16* __restrict__ Vt) {
  const int P = blockIdx.x;
  const int c_all = P >> 5, within = P & 31;
  const int n_idx = within >> 3, i8 = within & 7;
  const int which = c_all >> 3;
  const int g = ((c_all & 7) << 3) | i8;  // m-group 0..63
  const int m0 = g * 128, n0 = n_idx * 128;

  const uint8_t* Ahb = (const uint8_t*)(Xh + (size_t)which * 4194304);
  const uint8_t* Alb = (const uint8_t*)(Xl + (size_t)which * 4194304);
  const uint8_t* Bhb = (const uint8_t*)(wt_hi + (size_t)which * 262144);
  const uint8_t* Blb = (const uint8_t*)(wt_lo + (size_t)which * 262144);
  const int tid = threadIdx.x, wave = tid >> 6, lane = tid & 63;
  const int l15 = lane & 15, l4 = lane >> 4;
  const int Am0 = (wave & 1) * 64, Bn0 = (wave >> 1) * 64;

  __shared__ bf16 sAh[128 * 32], sAl[128 * 32];  // 8 KB each
  __shared__ bf16 sBh[128 * 32], sBl[128 * 32];  // 8 KB each

  int aoff[2], boff[2], dstp[2];
#pragma unroll
  for (int p = 0; p < 2; p++) {
    int slot = p * 256 + tid;
    int row = slot >> 2, phys = slot & 3, lg = phys ^ (row & 3);
    aoff[p] = (m0 + row) * 1024 + lg * 16;
    boff[p] = (n0 + row) * 1024 + lg * 16;
    dstp[p] = slot * 16;
  }

  floatx4 acc[4][4];
#pragma unroll
  for (int i = 0; i < 4; i++)
#pragma unroll
    for (int j = 0; j < 4; j++) acc[i][j] = {0.f, 0.f, 0.f, 0.f};

  // prologue: issue stage(0)
#pragma unroll
  for (int p = 0; p < 2; p++) {
    GLD16(Ahb + aoff[p], (char*)sAh + dstp[p]);
    GLD16(Alb + aoff[p], (char*)sAl + dstp[p]);
    GLD16(Bhb + boff[p], (char*)sBh + dstp[p]);
    GLD16(Blb + boff[p], (char*)sBl + dstp[p]);
  }

  for (int kb = 0; kb < 512; kb += 32) {
    PIPE_TOP();  // stage(kb) landed

    bf16x8 ah[4], al[4], bhf[4], blf[4];
#pragma unroll
    for (int mt = 0; mt < 4; mt++) {
      int row = Am0 + mt * 16 + l15, r3 = row & 3;
      ah[mt] = *(const bf16x8*)((const char*)sAh + row * 64 + ((l4 ^ r3) * 16));
      al[mt] = *(const bf16x8*)((const char*)sAl + row * 64 + ((l4 ^ r3) * 16));
    }
#pragma unroll
    for (int nt = 0; nt < 4; nt++) {
      int row = Bn0 + nt * 16 + l15, r3 = row & 3;
      bhf[nt] = *(const bf16x8*)((const char*)sBh + row * 64 + ((l4 ^ r3) * 16));
      blf[nt] = *(const bf16x8*)((const char*)sBl + row * 64 + ((l4 ^ r3) * 16));
    }

    LGKM_BARRIER();  // all waves consumed -> safe to overwrite

    if (kb + 32 < 512) {
      const int nkb = kb + 32;
#pragma unroll
      for (int p = 0; p < 2; p++) {
        GLD16(Ahb + aoff[p] + nkb * 2, (char*)sAh + dstp[p]);
        GLD16(Alb + aoff[p] + nkb * 2, (char*)sAl + dstp[p]);
        GLD16(Bhb + boff[p] + nkb * 2, (char*)sBh + dstp[p]);
        GLD16(Blb + boff[p] + nkb * 2, (char*)sBl + dstp[p]);
      }
    }

    __builtin_amdgcn_s_setprio(1);
#pragma unroll
    for (int nt = 0; nt < 4; nt++) {
#pragma unroll
      for (int mt = 0; mt < 4; mt++) {
        acc[mt][nt] = MFMA16(ah[mt], bhf[nt], acc[mt][nt]);
        acc[mt][nt] = MFMA16(ah[mt], blf[nt], acc[mt][nt]);
        acc[mt][nt] = MFMA16(al[mt], bhf[nt], acc[mt][nt]);
      }
    }
    __builtin_amdgcn_s_setprio(0);
  }

  const float scale = (which == 0) ? 0.125f : (which == 1) ? 1.44269504f : 1.0f;
#pragma unroll
  for (int mt = 0; mt < 4; mt++) {
#pragma unroll
    for (int nt = 0; nt < 4; nt++) {
      int m_base = m0 + Am0 + mt * 16 + l4 * 4;  // 4 consecutive rows (s)
      int n = n0 + Bn0 + nt * 16 + l15;          // h*64+d
      int h = (n >> 6) & 7, d = n & 63;
      if (which == 2) {
        // slot-permuted packed V^T store: keys 16t+4q+r -> column 8q+4t+r
        int kbase = m_base & 2047, b = m_base >> 11;
        int a32 = kbase & ~31, v = (kbase >> 2) & 7;
        int sbase = a32 + 8 * (v & 3) + 4 * (v >> 2);
        bf16x4 pv;
#pragma unroll
        for (int r = 0; r < 4; r++) pv[r] = (bf16)acc[mt][nt][r];
        *(bf16x4*)&Vt[((size_t)(b * 8 + h) * 64 + d) * 2048 + sbase] = pv;
      } else {
#pragma unroll
        for (int r = 0; r < 4; r++) {
          int m = m_base + r;
          int b = m >> 11, s = m & 2047;
          float v = acc[mt][nt][r] * scale;
          size_t o = ((size_t)(b * 8 + h) * 2048 + s) * 64 + d;
          if (which == 0) {
            bf16 hi, lo;
            split2(v, hi, lo);
            Q_hi[o] = hi; Q_lo[o] = lo;
          } else {
            K[o] = (bf16)v;  // single bf16 K
          }
        }
      }
    }
  }
}

// ---------------------------------------------------------------------------
// Flash attention (R22 structure; stage-issue hoisted before ds_reads):
// grid 1024, block 256 = 4 waves; wave w owns keys [32w,32w+32). K/V dbuf
// (66.5KB) + counted-wait pipeline. Per iter: PIPE_TOP -> issue stage(j+1)
// into buf^1 (safe: buf^1's readers passed the barrier) -> ds_read buf[cur]
// -> QK -> exp -> PV. Single-phase mq-distributed epilogue.
// ---------------------------------------------------------------------------
__global__ __launch_bounds__(256, 2) void k_flash(
    const bf16* __restrict__ Q_hi, const bf16* __restrict__ Q_lo,
    const bf16* __restrict__ K, const bf16* __restrict__ Vt,
    bf16* __restrict__ O_hi, bf16* __restrict__ O_lo) {
  const int P = blockIdx.x;
  const int hi4 = P >> 8, rem = P & 255;
  const int qt = rem >> 3;
  const int bh = hi4 * 8 + (rem & 7);
  const int b = bh >> 3, h = bh & 7;
  const int tid = threadIdx.x, wave = tid >> 6, lane = tid & 63;
  const int l15 = lane & 15, l4 = lane >> 4;
  const int q0 = qt * 64;

  // buf c: sK @ c*32768 (16KB) | sV @ c*32768+16384 (16KB); lbuf @ 65536 (1KB)
  __shared__ char smem[2 * 32768 + 1024];
  float* lbuf = (float*)(smem + 65536);

  const uint8_t* Kb = (const uint8_t*)K + (size_t)bh * 2048 * 128;
  const uint8_t* Vb = (const uint8_t*)Vt + (size_t)bh * 64 * 4096;
  int koff[4], voff[4], dst[4];
#pragma unroll
  for (int p = 0; p < 4; p++) {
    int slot = p * 256 + tid;
    {
      int row = slot >> 3, phys = slot & 7, lg = phys ^ (row & 7);
      koff[p] = row * 128 + lg * 16;
    }
    {
      int row = slot >> 4, phys = slot & 15, lg = phys ^ (row & 15);
      voff[p] = row * 4096 + lg * 16;
    }
    dst[p] = slot * 16;
  }

  // prologue: issue stage j0=0 into buf 0 (in flight under Q loads)
#pragma unroll
  for (int p = 0; p < 4; p++) {
    GLD16(Kb + koff[p], smem + dst[p]);
    GLD16(Vb + voff[p], smem + 16384 + dst[p]);
  }

  // Q fragments (B operand): lane holds Q[q=l15][dh=l4*8+j]
  bf16x8 qh[4][2], ql[4][2];
#pragma unroll
  for (int nt = 0; nt < 4; nt++) {
    const bf16* ph = Q_hi + ((size_t)bh * 2048 + q0 + nt * 16 + l15) * 64 + l4 * 8;
    const bf16* pl = Q_lo + ((size_t)bh * 2048 + q0 + nt * 16 + l15) * 64 + l4 * 8;
    qh[nt][0] = *(const bf16x8*)ph;
    qh[nt][1] = *(const bf16x8*)(ph + 32);
    ql[nt][0] = *(const bf16x8*)pl;
    ql[nt][1] = *(const bf16x8*)(pl + 32);
  }

  float lp[4] = {0.f, 0.f, 0.f, 0.f};  // l partial per q-tile (q = nt*16+l15)
  floatx4 oacc[4][4];
#pragma unroll
  for (int i = 0; i < 4; i++)
#pragma unroll
    for (int j = 0; j < 4; j++) oacc[i][j] = {0.f, 0.f, 0.f, 0.f};

  int cur = 0;
  for (int j0 = 0; j0 < 2048; j0 += 128) {
    PIPE_TOP();  // stage(j0) landed (issued last iter); all waves synced

    // issue next key-tile FIRST (independent of this tile's ds_reads;
    // buf^1's previous readers all passed the barrier above)
    if (j0 + 128 < 2048) {
      char* nb = smem + (cur ^ 1) * 32768;
      const size_t nj = (size_t)(j0 + 128);
#pragma unroll
      for (int p = 0; p < 4; p++) {
        GLD16(Kb + nj * 128 + koff[p], nb + dst[p]);
        GLD16(Vb + nj * 2 + voff[p], nb + 16384 + dst[p]);
      }
    }

    const char* sK = smem + cur * 32768;
    const char* sV = sK + 16384;

    // K/V fragments -> regs (12 x ds_read_b128)
    bf16x8 kf[2][2];  // [ks][kt]
#pragma unroll
    for (int kt = 0; kt < 2; kt++) {
      int row = wave * 32 + kt * 16 + l15, r7 = row & 7;
#pragma unroll
      for (int ks = 0; ks < 2; ks++)
        kf[ks][kt] =
            *(const bf16x8*)(sK + row * 128 + (((ks * 4 + l4) ^ r7) * 16));
    }
    bf16x8 vf[4];
#pragma unroll
    for (int nt = 0; nt < 4; nt++) {
      int row = nt * 16 + l15;
      vf[nt] =
          *(const bf16x8*)(sV + row * 256 + (((wave * 4 + l4) ^ l15) * 16));
    }

    // S^T = K Q^T - 24: sc[kt][nt] C-tile: row=key(16), col=q (l15)
    floatx4 sc[2][4];
#pragma unroll
    for (int kt = 0; kt < 2; kt++)
#pragma unroll
      for (int nt = 0; nt < 4; nt++)
        sc[kt][nt] = {-24.f, -24.f, -24.f, -24.f};
#pragma unroll
    for (int ks = 0; ks < 2; ks++) {
#pragma unroll
      for (int nt = 0; nt < 4; nt++) {
        sc[0][nt] = MFMA16(kf[ks][0], qh[nt][ks], sc[0][nt]);
        sc[0][nt] = MFMA16(kf[ks][0], ql[nt][ks], sc[0][nt]);
        sc[1][nt] = MFMA16(kf[ks][1], qh[nt][ks], sc[1][nt]);
        sc[1][nt] = MFMA16(kf[ks][1], ql[nt][ks], sc[1][nt]);
      }
    }

    // p = exp2(s); pf[nt] directly the PV A-operand (slot = quad*8 + 4*kt + r)
    bf16x8 pf[4];
#pragma unroll
    for (int nt = 0; nt < 4; nt++) {
#pragma unroll
      for (int r = 0; r < 4; r++) {
        float p0 = __builtin_amdgcn_exp2f(sc[0][nt][r]);
        float p1 = __builtin_amdgcn_exp2f(sc[1][nt][r]);
        lp[nt] += p0 + p1;
        pf[nt][r] = (bf16)p0;
        pf[nt][4 + r] = (bf16)p1;
      }
    }

    // O += P V over this wave's 32 slots
#pragma unroll
    for (int nt = 0; nt < 4; nt++) {
#pragma unroll
      for (int mq = 0; mq < 4; mq++)
        oacc[mq][nt] = MFMA16(pf[mq], vf[nt], oacc[mq][nt]);
    }
    cur ^= 1;
  }

  // ---- epilogue: single-phase mq-distributed reduction + write ----
#pragma unroll
  for (int nt = 0; nt < 4; nt++) {
    lp[nt] += __shfl_xor(lp[nt], 16, 64);
    lp[nt] += __shfl_xor(lp[nt], 32, 64);
  }
  __syncthreads();  // all waves done with K/V buffers before aliasing red

  if (l4 == 0) {
#pragma unroll
    for (int nt = 0; nt < 4; nt++) lbuf[wave * 64 + nt * 16 + l15] = lp[nt];
  }
  // red slice (src, mq, nt): base floatx4 index (src*16 + mq*4 + nt)*64 + lane
  floatx4* red = (floatx4*)smem;
#pragma unroll
  for (int mq = 0; mq < 4; mq++) {
    if (mq != wave) {
#pragma unroll
      for (int nt = 0; nt < 4; nt++)
        red[(wave * 16 + mq * 4 + nt) * 64 + lane] = oacc[mq][nt];
    }
  }
  __syncthreads();

  {
    const int mq = wave;  // this wave finalizes q rows q0 + mq*16 .. +16
    floatx4 fin[4];
#pragma unroll
    for (int nt = 0; nt < 4; nt++) {
      floatx4 s0 = (wave == 0) ? oacc[mq][nt]
                               : red[(0 * 16 + mq * 4 + nt) * 64 + lane];
      floatx4 s1 = (wave == 1) ? oacc[mq][nt]
                               : red[(1 * 16 + mq * 4 + nt) * 64 + lane];
      floatx4 s2 = (wave == 2) ? oacc[mq][nt]
                               : red[(2 * 16 + mq * 4 + nt) * 64 + lane];
      floatx4 s3 = (wave == 3) ? oacc[mq][nt]
                               : red[(3 * 16 + mq * 4 + nt) * 64 + lane];
      fin[nt] = s0 + ((s1 + s2) + s3);
    }
    float ltw = lbuf[mq * 16 + l15] + lbuf[64 + mq * 16 + l15] +
                lbuf[128 + mq * 16 + l15] + lbuf[192 + mq * 16 + l15];
    float rlw[4];
#pragma unroll
    for (int r = 0; r < 4; r++)
      rlw[r] = 1.0f / __shfl(ltw, (lane & 48) | (l4 * 4 + r), 64);
#pragma unroll
    for (int nt = 0; nt < 4; nt++) {
#pragma unroll
      for (int r = 0; r < 4; r++) {
        float v = fin[nt][r] * rlw[r];
        int gs = q0 + mq * 16 + l4 * 4 + r;
        int gd = h * 64 + nt * 16 + l15;
        size_t o = ((size_t)b * 2048 + gs) * 512 + gd;
        bf16 hi, lo;
        split2(v, hi, lo);
        O_hi[o] = hi;
        O_lo[o] = lo;
      }
    }
  }
}

// ---------------------------------------------------------------------------
// Output projection, 64x128 C-tile, BK=32, single-buffer (24KB) two-phase
// sync + setprio. grid 512, m-major -> 2 blocks/CU. (R22-exact)
// ---------------------------------------------------------------------------
__global__ __launch_bounds__(256, 2) void k_proj_out(
    const bf16* __restrict__ O_hi, const bf16* __restrict__ O_lo,
    const bf16* __restrict__ wt_hi, const bf16* __restrict__ wt_lo,
    float* __restrict__ out) {
  const int P = blockIdx.x;
  const int g = P & 127, n_idx = P >> 7;
  const int m0 = g * 64, n0 = n_idx * 128;

  const uint8_t* Ahb = (const uint8_t*)O_hi;
  const uint8_t* Alb = (const uint8_t*)O_lo;
  const uint8_t* Bhb = (const uint8_t*)(wt_hi + (size_t)3 * 262144);
  const uint8_t* Blb = (const uint8_t*)(wt_lo + (size_t)3 * 262144);
  const int tid = threadIdx.x, wave = tid >> 6, lane = tid & 63;
  const int l15 = lane & 15, l4 = lane >> 4;
  const int Am0 = (wave & 1) * 32, Bn0 = (wave >> 1) * 64;

  __shared__ bf16 sAh[64 * 32], sAl[64 * 32];    // 4 KB each
  __shared__ bf16 sBh[128 * 32], sBl[128 * 32];  // 8 KB each

  int aoff, adst;
  {
    int slot = tid;
    int row = slot >> 2, phys = slot & 3, lg = phys ^ (row & 3);
    aoff = (m0 + row) * 1024 + lg * 16;
    adst = slot * 16;
  }
  int boff[2], bdst[2];
#pragma unroll
  for (int p = 0; p < 2; p++) {
    int slot = p * 256 + tid;
    int row = slot >> 2, phys = slot & 3, lg = phys ^ (row & 3);
    boff[p] = (n0 + row) * 1024 + lg * 16;
    bdst[p] = slot * 16;
  }

  floatx4 acc[2][4];
#pragma unroll
  for (int i = 0; i < 2; i++)
#pragma unroll
    for (int j = 0; j < 4; j++) acc[i][j] = {0.f, 0.f, 0.f, 0.f};

  // prologue: issue stage(0)
  GLD16(Ahb + aoff, (char*)sAh + adst);
  GLD16(Alb + aoff, (char*)sAl + adst);
#pragma unroll
  for (int p = 0; p < 2; p++) {
    GLD16(Bhb + boff[p], (char*)sBh + bdst[p]);
    GLD16(Blb + boff[p], (char*)sBl + bdst[p]);
  }

  for (int kb = 0; kb < 512; kb += 32) {
    PIPE_TOP();

    bf16x8 ah[2], al[2], bhf[4], blf[4];
#pragma unroll
    for (int mt = 0; mt < 2; mt++) {
      int row = Am0 + mt * 16 + l15, r3 = row & 3;
      ah[mt] = *(const bf16x8*)((const char*)sAh + row * 64 + ((l4 ^ r3) * 16));
      al[mt] = *(const bf16x8*)((const char*)sAl + row * 64 + ((l4 ^ r3) * 16));
    }
#pragma unroll
    for (int nt = 0; nt < 4; nt++) {
      int row = Bn0 + nt * 16 + l15, r3 = row & 3;
      bhf[nt] = *(const bf16x8*)((const char*)sBh + row * 64 + ((l4 ^ r3) * 16));
      blf[nt] = *(const bf16x8*)((const char*)sBl + row * 64 + ((l4 ^ r3) * 16));
    }

    LGKM_BARRIER();

    if (kb + 32 < 512) {
      const int nkb = kb + 32;
      GLD16(Ahb + aoff + nkb * 2, (char*)sAh + adst);
      GLD16(Alb + aoff + nkb * 2, (char*)sAl + adst);
#pragma unroll
      for (int p = 0; p < 2; p++) {
        GLD16(Bhb + boff[p] + nkb * 2, (char*)sBh + bdst[p]);
        GLD16(Blb + boff[p] + nkb * 2, (char*)sBl + bdst[p]);
      }
    }

    __builtin_amdgcn_s_setprio(1);
#pragma unroll
    for (int nt = 0; nt < 4; nt++) {
#pragma unroll
      for (int mt = 0; mt < 2; mt++) {
        acc[mt][nt] = MFMA16(ah[mt], bhf[nt], acc[mt][nt]);
        acc[mt][nt] = MFMA16(ah[mt], blf[nt], acc[mt][nt]);
        acc[mt][nt] = MFMA16(al[mt], bhf[nt], acc[mt][nt]);
      }
    }
    __builtin_amdgcn_s_setprio(0);
  }
#pragma unroll
  for (int mt = 0; mt < 2; mt++) {
#pragma unroll
    for (int nt = 0; nt < 4; nt++) {
#pragma unroll
      for (int r = 0; r < 4; r++) {
        int m = m0 + Am0 + mt * 16 + l4 * 4 + r;
        int n = n0 + Bn0 + nt * 16 + l15;
        out[(size_t)m * 512 + n] = acc[mt][nt][r];
      }
    }
  }
}

// ---------------------------------------------------------------------------
extern "C" void kernel_launch(void* const* d_in, const int* in_sizes, int n_in,
                              void* d_out, int out_size, void* d_ws, size_t ws_size,
                              hipStream_t stream) {
  (void)in_sizes; (void)n_in; (void)out_size; (void)ws_size;
  const float* Xq = (const float*)d_in[0];
  const float* Xk = (const float*)d_in[1];
  const float* Xv = (const float*)d_in[2];
  const float* Wq = (const float*)d_in[3];
  const float* Wk = (const float*)d_in[4];
  const float* Wv = (const float*)d_in[5];
  const float* Wo = (const float*)d_in[6];
  float* out = (float*)d_out;

  char* ws = (char*)d_ws;
  size_t off = 0;
  auto alloc = [&](size_t n) {
    void* p = ws + off;
    off += (n + 255) & ~(size_t)255;
    return p;
  };
  const size_t NW = 4 * 262144;
  const size_t NE = 4194304;       // 4*2048*512
  const size_t NX = 3 * 4194304;   // all three X inputs
  bf16* wt_hi = (bf16*)alloc(NW * 2);
  bf16* wt_lo = (bf16*)alloc(NW * 2);
  bf16* Qh = (bf16*)alloc(NE * 2);
  bf16* Ql = (bf16*)alloc(NE * 2);
  bf16* Kk = (bf16*)alloc(NE * 2);
  bf16* Vt = (bf16*)alloc(NE * 2);
  // Xh/Xl alias Oh/Ol: Xh,Xl dead before flash writes Oh,Ol.
  char* shared_region = (char*)alloc(2 * NX * 2);
  bf16* Xh = (bf16*)shared_region;
  bf16* Xl = Xh + NX;
  bf16* Oh = (bf16*)shared_region;
  bf16* Ol = Oh + NE;

  k_split_w<<<dim3(8, 8, 4), dim3(256), 0, stream>>>(Wq, Wk, Wv, Wo, wt_hi, wt_lo);
  k_split_x<<<dim3(2048), dim3(256), 0, stream>>>(Xq, Xk, Xv, Xh, Xl);
  k_proj_qkv<<<dim3(768), dim3(256), 0, stream>>>(Xh, Xl, wt_hi, wt_lo,
                                                  Qh, Ql, Kk, Vt);
  k_flash<<<dim3(1024), dim3(256), 0, stream>>>(Qh, Ql, Kk, Vt, Oh, Ol);
  k_proj_out<<<dim3(512), dim3(256), 0, stream>>>(Oh, Ol, wt_hi, wt_lo, out);
}